// Round 19
// baseline (183.666 us; speedup 1.0000x reference)
//
#include <hip/hip_runtime.h>
#include <hip/hip_bf16.h>

typedef __attribute__((ext_vector_type(8))) short bf16x8;
typedef __attribute__((ext_vector_type(4))) float f32x4;
typedef __attribute__((ext_vector_type(4))) int i32x4;

#define D128 128
#define IMG_SHORTS 16384          // one full W frag-image: 32 frags x 64 lanes x 8 bf16
#define XB_OFF 65536              // xb at 128 KiB into d_ws (in shorts)
#define WSH_HALF 24576            // 48KB in shorts: 3 chunks x 16 frags x 512 shorts

__device__ __forceinline__ short f2bf(float f) {
    union { float f; unsigned u; } v; v.f = f;
    unsigned r = (v.u + 0x7FFFu + ((v.u >> 16) & 1u)) >> 16;  // RNE
    return (short)r;
}

__device__ __forceinline__ short f2bf_h(float f) {
    __hip_bfloat16 h = __float2bfloat16(f);
    short s;
    __builtin_memcpy(&s, &h, sizeof(short));
    return s;
}

__device__ __forceinline__ bf16x8 pack8(f32x4 a, f32x4 b) {
    bf16x8 r;
    r[0] = f2bf_h(a[0]); r[1] = f2bf_h(a[1]); r[2] = f2bf_h(a[2]); r[3] = f2bf_h(a[3]);
    r[4] = f2bf_h(b[0]); r[5] = f2bf_h(b[1]); r[6] = f2bf_h(b[2]); r[7] = f2bf_h(b[3]);
    return r;
}

// Redistribute a 16B fragment across lanes: dest lane (fr=l&15, lhi=l>>4)
// pulls from source lane fr*4+lhi (which loaded row fr, quarter lhi,
// quad-coalesced). Fixed bijective permutation -> full-rate ds_bpermute.
__device__ __forceinline__ bf16x8 bperm8(int addr, bf16x8 v) {
    i32x4 iv = __builtin_bit_cast(i32x4, v);
    i32x4 ov;
#pragma unroll
    for (int i = 0; i < 4; ++i)
        ov[i] = __builtin_amdgcn_ds_bpermute(addr, iv[i]);
    return __builtin_bit_cast(bf16x8, ov);
}

__device__ __forceinline__ void gload_lds16(const short* g, short* l) {
    __builtin_amdgcn_global_load_lds(
        (const __attribute__((address_space(1))) unsigned int*)(const void*)g,
        (__attribute__((address_space(3))) unsigned int*)(void*)l, 16, 0, 0);
}

// W (3*128 x 128 fp32 row-major) -> 3 A-operand fragment images (src,dst,e):
// img[c][frag=mt*4+ks][lane][j] = W[c*128 + ks*32 + (lane>>4)*8 + j][mt*16 + (lane&15)]
__global__ __launch_bounds__(256) void wt_kernel(const float* __restrict__ W,
                                                 short* __restrict__ Wimg) {
    const int c    = blockIdx.x >> 3;
    const int frag = (blockIdx.x & 7) * 4 + (threadIdx.x >> 6);
    const int lane = threadIdx.x & 63;
    const int mt = frag >> 2, ks = frag & 3;
    const int m  = mt * 16 + (lane & 15);
    const int k0 = ks * 32 + (lane >> 4) * 8;
    bf16x8 v;
#pragma unroll
    for (int j = 0; j < 8; ++j)
        v[j] = f2bf(W[(size_t)(c * 128 + k0 + j) * D128 + m]);
    *reinterpret_cast<bf16x8*>(
        &Wimg[((size_t)c * 32 + frag) * 64 * 8 + (size_t)lane * 8]) = v;
}

// x (fp32) -> xb (bf16), 8 elems/thread.
__global__ __launch_bounds__(256) void xb_kernel(const float* __restrict__ x,
                                                 short* __restrict__ xb) {
    const size_t i = ((size_t)blockIdx.x * 256 + threadIdx.x) * 8;
    f32x4 v0 = reinterpret_cast<const f32x4*>(x + i)[0];
    f32x4 v1 = reinterpret_cast<const f32x4*>(x + i)[1];
    *reinterpret_cast<bf16x8*>(xb + i) = pack8(v0, v1);
}

// Column-split fused kernel: grid 512 = 256 row-groups x 2 col-halves.
// Block (rb, h): rows of tiles t0..t1 (128/tile), output cols [h*64, h*64+64).
// Pairs (rb, rb+256) share all input rows and land on the SAME XCD
// (256 % 8 == 0) -> duplicated e reads should L2-hit.
// LDS = 48KB W only (2 blocks/CU, 16 independent waves/CU). NO row buffers:
// gathers load quad-coalesced (64B/quad) into regs and are redistributed to
// fragment shape via ds_bpermute (fixed lane permutation). No loop barriers,
// no manual vmcnt (compiler-managed waits via data deps, R18-proven).
__global__ __launch_bounds__(512, 4) void fused_kernel(
        const short* __restrict__ xb,
        const float* __restrict__ e,
        const short* __restrict__ Wimg,
        const int*  __restrict__ src_idx,
        const int*  __restrict__ dst_idx,
        float* __restrict__ out,
        int E, int ntiles)
{
    __shared__ short lds[WSH_HALF];   // 48 KB: half-images of the 3 W chunks

    const int tid  = threadIdx.x;
    const int lane = tid & 63;
    const int w    = tid >> 6;            // 0..7
    const int r    = lane >> 2;           // row this lane's gather load serves
    const int q    = lane & 3;            // 16B quarter of the 64B span
    const int fr   = lane & 15;           // frag row this lane computes
    const int lhi  = lane >> 4;           // frag k-quarter
    const int bp   = ((lane & 15) * 4 + (lane >> 4)) * 4;   // bpermute byte addr

    const int h  = blockIdx.x >> 8;       // col half: 0 or 1
    const int rb = blockIdx.x & 255;      // row group

    // contiguous tile range for this row group
    const int per = ntiles >> 8;
    const int rem = ntiles & 255;
    const int t0  = rb * per + (rb < rem ? rb : rem);
    const int t1  = t0 + per + (rb < rem ? 1 : 0);

    // ---- stage the 3 half-images (3072 x 16B units, 6/thread) ----
    // source: chunk c, frags [h*16, h*16+16) = shorts (c*32+h*16)*512 ..
#pragma unroll
    for (int jj = 0; jj < 6; ++jj) {
        int u    = jj * 512 + tid;        // 0..3071
        int c    = u >> 10;               // 0..2
        int rm   = u & 1023;              // 16B unit within the 16KB half-image
        gload_lds16(Wimg + ((size_t)(c * 32 + h * 16)) * 512 + (size_t)rm * 8,
                    &lds[u * 8]);
    }
    int rp = t0 * 128 + w * 16 + r;
    int si = src_idx[rp];
    int di = dst_idx[rp];
    asm volatile("" ::: "memory");
    asm volatile("s_waitcnt vmcnt(0)" ::: "memory");
    __builtin_amdgcn_s_barrier();          // the only barrier

    // ---- prologue: src[t0] quad-coalesced reg loads, e[t0], idx[t0+1] ----
    bf16x8 sl[4];
#pragma unroll
    for (int ks = 0; ks < 4; ++ks)
        sl[ks] = *reinterpret_cast<const bf16x8*>(
            xb + (size_t)si * D128 + ks * 32 + q * 8);
    f32x4 ev[8];
    {
        const float* pe = e + (size_t)(t0 * 128 + w * 16 + fr) * D128;
#pragma unroll
        for (int ks = 0; ks < 4; ++ks) {
            ev[2 * ks]     = reinterpret_cast<const f32x4*>(pe + ks * 32 + lhi * 8)[0];
            ev[2 * ks + 1] = reinterpret_cast<const f32x4*>(pe + ks * 32 + lhi * 8)[1];
        }
    }
    int rpn = (t0 + 1) * 128 + w * 16 + r;
    if (rpn >= E) rpn = E - 1;
    int sn = src_idx[rpn];
    int dn = dst_idx[rpn];
    asm volatile("" ::: "memory");

    for (int t = t0; t < t1; ++t) {
        const int rn = t * 128 + w * 16 + fr;    // compute/e/store row

        // ---- issue dst[t] + src[t+1] quad-coalesced reg loads ----
        bf16x8 dl[4], nl[4];
#pragma unroll
        for (int ks = 0; ks < 4; ++ks)
            dl[ks] = *reinterpret_cast<const bf16x8*>(
                xb + (size_t)di * D128 + ks * 32 + q * 8);
#pragma unroll
        for (int ks = 0; ks < 4; ++ks)
            nl[ks] = *reinterpret_cast<const bf16x8*>(
                xb + (size_t)sn * D128 + ks * 32 + q * 8);
        asm volatile("" ::: "memory");

        f32x4 acc[4];
#pragma unroll
        for (int mt = 0; mt < 4; ++mt) acc[mt] = (f32x4){0.f, 0.f, 0.f, 0.f};

        // ---- chunk 0: src (bpermute forces the wait on sl) ----
#pragma unroll
        for (int ks = 0; ks < 4; ++ks) {
            bf16x8 bfr = bperm8(bp, sl[ks]);
#pragma unroll
            for (int mt = 0; mt < 4; ++mt) {
                bf16x8 a = *reinterpret_cast<const bf16x8*>(
                    &lds[((0 * 16 + mt * 4 + ks) * 64 + lane) * 8]);
                acc[mt] = __builtin_amdgcn_mfma_f32_16x16x32_bf16(a, bfr, acc[mt], 0, 0, 0);
            }
        }

        // ---- chunk 1: dst ----
#pragma unroll
        for (int ks = 0; ks < 4; ++ks) {
            bf16x8 bfr = bperm8(bp, dl[ks]);
#pragma unroll
            for (int mt = 0; mt < 4; ++mt) {
                bf16x8 a = *reinterpret_cast<const bf16x8*>(
                    &lds[((1 * 16 + mt * 4 + ks) * 64 + lane) * 8]);
                acc[mt] = __builtin_amdgcn_mfma_f32_16x16x32_bf16(a, bfr, acc[mt], 0, 0, 0);
            }
        }

        // ---- chunk 2: e (pack then MFMA; ev arrived an iteration ago) ----
#pragma unroll
        for (int ks = 0; ks < 4; ++ks) {
            bf16x8 be = pack8(ev[2 * ks], ev[2 * ks + 1]);
#pragma unroll
            for (int mt = 0; mt < 4; ++mt) {
                bf16x8 a = *reinterpret_cast<const bf16x8*>(
                    &lds[((2 * 16 + mt * 4 + ks) * 64 + lane) * 8]);
                acc[mt] = __builtin_amdgcn_mfma_f32_16x16x32_bf16(a, be, acc[mt], 0, 0, 0);
            }
        }

        // ---- stores: cols h*64 + mt*16 + lhi*4 .. +3 (4 x dwordx4) ----
        float* po = out + (size_t)rn * D128 + h * 64 + lhi * 4;
#pragma unroll
        for (int mt = 0; mt < 4; ++mt)
            *reinterpret_cast<f32x4*>(po + mt * 16) = acc[mt];
        asm volatile("" ::: "memory");

        // ---- next-iteration loads: e[t+1], idx[t+2]; promote indices ----
        si = sn; di = dn;
        sl[0] = nl[0]; sl[1] = nl[1]; sl[2] = nl[2]; sl[3] = nl[3];
        {
            int ern = (t + 1) * 128 + w * 16 + fr;
            if (ern >= E) ern = E - 1;
            const float* pe = e + (size_t)ern * D128;
#pragma unroll
            for (int ks = 0; ks < 4; ++ks) {
                ev[2 * ks]     = reinterpret_cast<const f32x4*>(pe + ks * 32 + lhi * 8)[0];
                ev[2 * ks + 1] = reinterpret_cast<const f32x4*>(pe + ks * 32 + lhi * 8)[1];
            }
        }
        int rp2 = (t + 2) * 128 + w * 16 + r;
        if (rp2 >= E) rp2 = E - 1;
        sn = src_idx[rp2];
        dn = dst_idx[rp2];
        asm volatile("" ::: "memory");
    }
}

extern "C" void kernel_launch(void* const* d_in, const int* in_sizes, int n_in,
                              void* d_out, int out_size, void* d_ws, size_t ws_size,
                              hipStream_t stream) {
    const float* x = (const float*)d_in[0];
    const float* e = (const float*)d_in[1];
    const float* W = (const float*)d_in[2];
    const int* src = (const int*)d_in[3];
    const int* dst = (const int*)d_in[4];
    float* out = (float*)d_out;

    short* Wimg = (short*)d_ws;                 // 3 x 32 KB frag images
    short* xb   = (short*)d_ws + XB_OFF;        // 100000*128 bf16 = 25.6 MB

    const int N = in_sizes[0] / D128;           // 100000
    const int E = in_sizes[3];                  // 400000
    const int ntiles = E / 128;                 // 3125 (exact)

    wt_kernel<<<24, 256, 0, stream>>>(W, Wimg);
    xb_kernel<<<(N * D128) / (256 * 8), 256, 0, stream>>>(x, xb);
    fused_kernel<<<512, 512, 0, stream>>>(xb, e, Wimg, src, dst, out, E, ntiles);
}